// Round 5
// baseline (240.001 us; speedup 1.0000x reference)
//
#include <hip/hip_runtime.h>
#include <hip/hip_bf16.h>

// CrossWinAttention — bf16 MFMA pipeline, round 4 (resubmit; round 4 never ran).
// B=2, N=6, X=Y=W1=W2=8, D=128, HEADS=4, DIM_HEAD=32; L=64, Q=384, TOK=49152.
//
//   0) transpose_w_kernel : wq/wk/wv (f32 [d][j]) -> bf16 [j][d]
//   1) ln_proj_all        : LN + MFMA proj; coalesced stores via swizzled LDS;
//                           V written TRANSPOSED to global (vpt[bl][h][d][k])
//   2) attn_mfma_kernel   : no LDS staging (K,Q,Vt direct from global/L2),
//                           no barriers, no max-tracking; ones-MFMA row sums
//   3) proj_skip_mean     : mean over N + f32 GEMM + bias + skip, 512 blocks

typedef __attribute__((ext_vector_type(8))) __bf16 bf16x8;
typedef __attribute__((ext_vector_type(4))) float f32x4;
typedef __attribute__((ext_vector_type(8))) unsigned short u16x8;

constexpr int BB  = 2;
constexpr int LL  = 64;
constexpr int QQ  = 384;
constexpr int TOK = BB * LL * QQ;  // 49152
constexpr float EPSF = 1e-5f;
constexpr float QSCALE = 0.17677669529663687f;  // 32^-0.5

__device__ __forceinline__ unsigned short f2bf(float x) {
  union { float f; unsigned u; } v; v.f = x;
  const unsigned r = v.u + 0x7FFFu + ((v.u >> 16) & 1u);  // RNE
  return (unsigned short)(r >> 16);
}
__device__ __forceinline__ unsigned short f2bf_trunc(float x) {
  union { float f; unsigned u; } v; v.f = x;
  return (unsigned short)(v.u >> 16);
}

// ---------------------------------------------------------------------------
// Kernel 0: W transpose + bf16 cast.
// ---------------------------------------------------------------------------
__global__ __launch_bounds__(256) void transpose_w_kernel(
    const float* __restrict__ wq, const float* __restrict__ wk,
    const float* __restrict__ wv, unsigned short* __restrict__ tq,
    unsigned short* __restrict__ tk, unsigned short* __restrict__ tv)
{
  const int e = blockIdx.x * 256 + threadIdx.x;  // 0..16383
  const int d = e >> 7, j = e & 127;
  const int o = j * 128 + d;
  tq[o] = f2bf(wq[e]);
  tk[o] = f2bf(wk[e]);
  tv[o] = f2bf(wv[e]);
}

// ---------------------------------------------------------------------------
// Kernel 1: fused q/k/v LN + MFMA projection, coalesced output stores.
// 2304 blocks; block = 64 tokens of one tensor (fixed (b,l), 64-aligned t).
// ---------------------------------------------------------------------------
__global__ __launch_bounds__(256) void ln_proj_all(
    const float* __restrict__ inq, const float* __restrict__ ink,
    const float* __restrict__ inv,
    const float* __restrict__ gq, const float* __restrict__ bq,
    const float* __restrict__ gk, const float* __restrict__ bk,
    const float* __restrict__ gv, const float* __restrict__ bv,
    const unsigned short* __restrict__ wtq, const unsigned short* __restrict__ wtk,
    const unsigned short* __restrict__ wtv,
    const float* __restrict__ biq, const float* __restrict__ bik,
    const float* __restrict__ biv,
    unsigned short* __restrict__ oq, unsigned short* __restrict__ ok,
    unsigned short* __restrict__ ovt)
{
  __shared__ __align__(16) unsigned short Xs[64 * 128];  // 16KB, reused as Tr
  const int bid = blockIdx.x;
  const int seg = (bid >= 1536) ? 2 : (bid >= 768 ? 1 : 0);
  const float* in    = (seg == 0) ? inq : (seg == 1) ? ink : inv;
  const float* gamma = (seg == 0) ? gq  : (seg == 1) ? gk  : gv;
  const float* beta  = (seg == 0) ? bq  : (seg == 1) ? bk  : bv;
  const unsigned short* wt = (seg == 0) ? wtq : (seg == 1) ? wtk : wtv;
  const float* bias  = (seg == 0) ? biq : (seg == 1) ? bik : biv;
  const float scale  = (seg == 0) ? QSCALE : 1.0f;

  const int tid = threadIdx.x, wave = tid >> 6, lane = tid & 63;
  const int tile0 = (bid - seg * 768) * 64;
  const int sl = lane & 15;          // 16 lanes per token
  const float4* g4 = (const float4*)gamma;
  const float4* be4 = (const float4*)beta;
  const float4 g0 = g4[sl * 2], g1 = g4[sl * 2 + 1];
  const float4 b0 = be4[sl * 2], b1 = be4[sl * 2 + 1];

  for (int it = 0; it < 4; ++it) {
    const int tl = wave * 16 + it * 4 + (lane >> 4);
    const int tg = tile0 + tl;
    const int b = tg / 24576; const int rem = tg - b * 24576;
    const int l = rem / 384;  const int t = rem - l * 384;
    const int n = t >> 6, w = t & 63;
    const float4* src = (const float4*)(in + (((size_t)((b * 6 + n) * 64 + l) * 64 + w) << 7));
    const float4 a = src[sl * 2], c = src[sl * 2 + 1];
    float sum = a.x + a.y + a.z + a.w + c.x + c.y + c.z + c.w;
    float sq = a.x * a.x + a.y * a.y + a.z * a.z + a.w * a.w
             + c.x * c.x + c.y * c.y + c.z * c.z + c.w * c.w;
#pragma unroll
    for (int o = 8; o >= 1; o >>= 1) { sum += __shfl_xor(sum, o); sq += __shfl_xor(sq, o); }
    const float mean = sum * (1.f / 128.f);
    const float var = sq * (1.f / 128.f) - mean * mean;
    const float rstd = rsqrtf(var + EPSF);
    unsigned short u[8];
    u[0] = f2bf((a.x - mean) * rstd * g0.x + b0.x);
    u[1] = f2bf((a.y - mean) * rstd * g0.y + b0.y);
    u[2] = f2bf((a.z - mean) * rstd * g0.z + b0.z);
    u[3] = f2bf((a.w - mean) * rstd * g0.w + b0.w);
    u[4] = f2bf((c.x - mean) * rstd * g1.x + b1.x);
    u[5] = f2bf((c.y - mean) * rstd * g1.y + b1.y);
    u[6] = f2bf((c.z - mean) * rstd * g1.z + b1.z);
    u[7] = f2bf((c.w - mean) * rstd * g1.w + b1.w);
    unsigned short* dst = &Xs[(tl * 128 + sl * 8) ^ ((tl & 7) << 3)];
#pragma unroll
    for (int j = 0; j < 8; ++j) dst[j] = u[j];
  }
  __syncthreads();

  const int lr = lane & 15, lg = lane >> 4;
  f32x4 accn[8];
#pragma unroll
  for (int i = 0; i < 8; ++i) accn[i] = (f32x4)0.f;
#pragma unroll
  for (int ks = 0; ks < 4; ++ks) {
    const bf16x8 xa = *(const bf16x8*)&Xs[((wave * 16 + lr) * 128 + ks * 32 + lg * 8) ^ ((lr & 7) << 3)];
#pragma unroll
    for (int nt = 0; nt < 8; ++nt) {
      const bf16x8 wb = *(const bf16x8*)(wt + (size_t)(nt * 16 + lr) * 128 + ks * 32 + lg * 8);
      accn[nt] = __builtin_amdgcn_mfma_f32_16x16x32_bf16(xa, wb, accn[nt], 0, 0, 0);
    }
  }

  __syncthreads();  // all Xs reads done; reuse as transpose buffer
  unsigned short* Tr = Xs;

  if (seg < 2) {
    // Tr[row 64][col 128], swizzled; then coalesced row-major b128 stores.
#pragma unroll
    for (int nt = 0; nt < 8; ++nt) {
      const float bvv = bias[nt * 16 + lr];
#pragma unroll
      for (int r = 0; r < 4; ++r) {
        const int rowl = wave * 16 + lg * 4 + r;
        Tr[(rowl * 128 + nt * 16 + lr) ^ ((rowl & 7) << 3)] =
            f2bf((accn[nt][r] + bvv) * scale);
      }
    }
    __syncthreads();
    unsigned short* out = (seg == 0) ? oq : ok;
#pragma unroll
    for (int i = 0; i < 4; ++i) {
      const int lin = i * 256 + tid;           // 0..1023
      const int rowl = lin >> 4, ch = lin & 15;
      const u16x8 val = *(const u16x8*)&Tr[(rowl * 128 + ch * 8) ^ ((rowl & 7) << 3)];
      *(u16x8*)(out + (size_t)(tile0 + rowl) * 128 + ch * 8) = val;
    }
  } else {
    // V: Tr[col 128][row 64] (transposed), then store vpt[bl][h][d][t].
#pragma unroll
    for (int nt = 0; nt < 8; ++nt) {
      const float bvv = bias[nt * 16 + lr];
#pragma unroll
      for (int r = 0; r < 4; ++r) {
        const int col = nt * 16 + lr;
        const int rowl = wave * 16 + lg * 4 + r;
        Tr[(col * 64 + rowl) ^ ((col & 7) << 3)] = f2bf(accn[nt][r] + bvv);
      }
    }
    __syncthreads();
    const int bwin = tile0 / 384;    // b*64 + l
    const int t0 = tile0 - bwin * 384;
#pragma unroll
    for (int i = 0; i < 4; ++i) {
      const int lin = i * 256 + tid;           // 0..1023
      const int col = lin >> 3, ch = lin & 7;  // col = h*32+d
      const u16x8 val = *(const u16x8*)&Tr[(col * 64 + ch * 8) ^ ((col & 7) << 3)];
      *(u16x8*)(ovt + ((size_t)bwin * 128 + col) * 384 + t0 + ch * 8) = val;
    }
  }
}

// ---------------------------------------------------------------------------
// Kernel 2: attention. Block = (bl, h, q-third): 1536 blocks, 4 waves,
// 32 q-rows (2 tiles) per wave. K/Q/Vt read straight from global (L2-hot);
// only per-wave P buffer in LDS. No barriers, no max-tracking (|s| <~ 10).
// ---------------------------------------------------------------------------
__global__ __launch_bounds__(256) void attn_mfma_kernel(
    const unsigned short* __restrict__ qp, const unsigned short* __restrict__ kp,
    const unsigned short* __restrict__ vpt, float* __restrict__ ao)
{
  __shared__ __align__(16) unsigned short Pl[4][512];   // per-wave [q16][k32]
  const int tid = threadIdx.x, wave = tid >> 6, lane = tid & 63;
  const int lr = lane & 15, lg = lane >> 4;
  const int bid = blockIdx.x;
  const int qs = bid % 3;
  const int hb = bid / 3;             // bl*4 + h
  const int h = hb & 3, bl = hb >> 2;
  const size_t base = (size_t)bl * (QQ * 128) + h * 32;
  const size_t vtb = (size_t)hb * 32 * 384;
  const int qbase = qs * 128 + wave * 32;

  bf16x8 qf[2];
#pragma unroll
  for (int t = 0; t < 2; ++t)
    qf[t] = *(const bf16x8*)(qp + base + (size_t)(qbase + t * 16 + lr) * 128 + lg * 8);

  f32x4 acc[2][2]; f32x4 sea[2];
#pragma unroll
  for (int t = 0; t < 2; ++t) {
    acc[t][0] = (f32x4)0.f; acc[t][1] = (f32x4)0.f; sea[t] = (f32x4)0.f;
  }
  bf16x8 ones;
#pragma unroll
  for (int i = 0; i < 8; ++i) ones[i] = (__bf16)1.0f;
  const f32x4 zf = (f32x4)0.f;

  for (int c = 0; c < 12; ++c) {
    const bf16x8 kf0 = *(const bf16x8*)(kp + base + (size_t)(c * 32 + lr) * 128 + lg * 8);
    const bf16x8 kf1 = *(const bf16x8*)(kp + base + (size_t)(c * 32 + 16 + lr) * 128 + lg * 8);
    const bf16x8 vf0 = *(const bf16x8*)(vpt + vtb + (size_t)lr * 384 + c * 32 + lg * 8);
    const bf16x8 vf1 = *(const bf16x8*)(vpt + vtb + (size_t)(16 + lr) * 384 + c * 32 + lg * 8);

#pragma unroll
    for (int t = 0; t < 2; ++t) {
      f32x4 s0 = __builtin_amdgcn_mfma_f32_16x16x32_bf16(qf[t], kf0, zf, 0, 0, 0);
      f32x4 s1 = __builtin_amdgcn_mfma_f32_16x16x32_bf16(qf[t], kf1, zf, 0, 0, 0);
#pragma unroll
      for (int r = 0; r < 4; ++r) {
        const float p0 = __expf(s0[r]);   // no max-subtract: |s| small by LN
        const float p1 = __expf(s1[r]);
        const int q = lg * 4 + r;
        // truncation bias cancels: sea uses the same truncated P
        Pl[wave][(q * 32 + lr) ^ ((q & 7) << 3)] = f2bf_trunc(p0);
        Pl[wave][(q * 32 + 16 + lr) ^ ((q & 7) << 3)] = f2bf_trunc(p1);
      }
      __builtin_amdgcn_sched_barrier(0);  // P-stores before pa-load
      const bf16x8 pa = *(const bf16x8*)&Pl[wave][(lr * 32 + lg * 8) ^ ((lr & 7) << 3)];
      acc[t][0] = __builtin_amdgcn_mfma_f32_16x16x32_bf16(pa, vf0, acc[t][0], 0, 0, 0);
      acc[t][1] = __builtin_amdgcn_mfma_f32_16x16x32_bf16(pa, vf1, acc[t][1], 0, 0, 0);
      sea[t]    = __builtin_amdgcn_mfma_f32_16x16x32_bf16(pa, ones, sea[t], 0, 0, 0);
      __builtin_amdgcn_sched_barrier(0);  // next P-stores after pa-load
    }
  }

#pragma unroll
  for (int t = 0; t < 2; ++t) {
#pragma unroll
    for (int r = 0; r < 4; ++r) {
      const float inv = 1.f / sea[t][r];
      const int row = qbase + t * 16 + lg * 4 + r;
      float* orow = ao + (size_t)(bl * QQ + row) * 128 + h * 32;
      orow[lr]      = acc[t][0][r] * inv;
      orow[16 + lr] = acc[t][1][r] * inv;
    }
  }
}

// ---------------------------------------------------------------------------
// Kernel 3: mean-over-N + final projection + bias + skip. 512 blocks x 16 rows.
// W read from global (L2 broadcast); X tile in padded LDS.
// ---------------------------------------------------------------------------
__global__ __launch_bounds__(256) void proj_skip_mean(
    const float* __restrict__ ao, const float* __restrict__ W,
    const float* __restrict__ bias, const float* __restrict__ skip,
    float* __restrict__ out)
{
  __shared__ float Xl[16][132];   // +4 pad kills bank conflicts
  const int tid = threadIdx.x;
  const int tile0 = blockIdx.x * 16;
  const float4* a4 = (const float4*)ao;
#pragma unroll
  for (int i = 0; i < 2; ++i) {
    const int e = i * 256 + tid;          // 0..511
    const int rl = e >> 5, f4 = e & 31;
    const int row = tile0 + rl;
    const int bl = row >> 6, w = row & 63;
    const size_t rbase = ((size_t)bl * 384 + w) * 32 + f4;
    float4 s = make_float4(0.f, 0.f, 0.f, 0.f);
#pragma unroll
    for (int n = 0; n < 6; ++n) {
      const float4 vv = a4[rbase + (size_t)n * 64 * 32];
      s.x += vv.x; s.y += vv.y; s.z += vv.z; s.w += vv.w;
    }
    const float inv6 = 1.f / 6.f;
    s.x *= inv6; s.y *= inv6; s.z *= inv6; s.w *= inv6;
    *(float4*)&Xl[rl][f4 * 4] = s;
  }
  __syncthreads();

  const int jg = tid & 31;      // float4 col
  const int rp = tid >> 5;      // row pair
  const float4* W4 = (const float4*)W;
  float4 acc0 = make_float4(0.f, 0.f, 0.f, 0.f);
  float4 acc1 = make_float4(0.f, 0.f, 0.f, 0.f);
#pragma unroll 4
  for (int d = 0; d < 128; ++d) {
    const float4 w4 = W4[d * 32 + jg];
    const float x0 = Xl[rp * 2][d];
    const float x1 = Xl[rp * 2 + 1][d];
    acc0.x += x0 * w4.x; acc0.y += x0 * w4.y; acc0.z += x0 * w4.z; acc0.w += x0 * w4.w;
    acc1.x += x1 * w4.x; acc1.y += x1 * w4.y; acc1.z += x1 * w4.z; acc1.w += x1 * w4.w;
  }

  const float4 bv = ((const float4*)bias)[jg];
  const float4* sk4 = (const float4*)skip;
  float4* out4 = (float4*)out;
#pragma unroll
  for (int p = 0; p < 2; ++p) {
    const int row = tile0 + rp * 2 + p;
    const float4 a = (p == 0) ? acc0 : acc1;
    const float4 sk = sk4[(size_t)row * 32 + jg];
    float4 o;
    o.x = a.x + bv.x + sk.x;
    o.y = a.y + bv.y + sk.y;
    o.z = a.z + bv.z + sk.z;
    o.w = a.w + bv.w + sk.w;
    out4[(size_t)row * 32 + jg] = o;
  }
}

// ---------------------------------------------------------------------------
extern "C" void kernel_launch(void* const* d_in, const int* in_sizes, int n_in,
                              void* d_out, int out_size, void* d_ws, size_t ws_size,
                              hipStream_t stream)
{
  const float* q     = (const float*)d_in[0];
  const float* k     = (const float*)d_in[1];
  const float* v     = (const float*)d_in[2];
  const float* skip  = (const float*)d_in[3];
  const float* lnq_g = (const float*)d_in[4];
  const float* lnq_b = (const float*)d_in[5];
  const float* lnk_g = (const float*)d_in[6];
  const float* lnk_b = (const float*)d_in[7];
  const float* lnv_g = (const float*)d_in[8];
  const float* lnv_b = (const float*)d_in[9];
  const float* wq = (const float*)d_in[10];
  const float* bq = (const float*)d_in[11];
  const float* wk = (const float*)d_in[12];
  const float* bk = (const float*)d_in[13];
  const float* wv = (const float*)d_in[14];
  const float* bv = (const float*)d_in[15];
  const float* wp = (const float*)d_in[16];
  const float* bp = (const float*)d_in[17];
  float* out = (float*)d_out;

  const size_t PROJ = (size_t)TOK * 128;  // elements
  unsigned short* qp  = (unsigned short*)d_ws;
  unsigned short* kp  = qp + PROJ;
  unsigned short* vpt = kp + PROJ;        // [bl][h][d][t] transposed V
  float* ao = (float*)(vpt + PROJ);
  unsigned short* wtq = (unsigned short*)(ao + PROJ);
  unsigned short* wtk = wtq + 16384;
  unsigned short* wtv = wtk + 16384;

  transpose_w_kernel<<<64, 256, 0, stream>>>(wq, wk, wv, wtq, wtk, wtv);
  ln_proj_all<<<2304, 256, 0, stream>>>(q, k, v, lnq_g, lnq_b, lnk_g, lnk_b,
                                        lnv_g, lnv_b, wtq, wtk, wtv,
                                        bq, bk, bv, qp, kp, vpt);
  attn_mfma_kernel<<<1536, 256, 0, stream>>>(qp, kp, vpt, ao);
  proj_skip_mean<<<512, 256, 0, stream>>>(ao, wp, bp, skip, out);
}

// Round 6
// 207.466 us; speedup vs baseline: 1.1568x; 1.1568x over previous
//
#include <hip/hip_runtime.h>
#include <hip/hip_bf16.h>

// CrossWinAttention — bf16 MFMA pipeline, round 6.
// B=2, N=6, X=Y=W1=W2=8, D=128, HEADS=4, DIM_HEAD=32; L=64, Q=384, TOK=49152.
//
//   0) transpose_w_kernel : wq/wk/wv/wp (f32 [k][j]) -> bf16 [j][k]
//   1) ln_proj_all        : LN + MFMA proj; V written TRANSPOSED (vpt[bl][hd][t])
//   2) attn_fused         : block = (bl, 8-w group), wave = head.
//                           swapped-operand QK^T -> packed b64 P-stores;
//                           PV + ones-MFMA row sums; then IN-BLOCK mean over n
//                           + bf16 MFMA output projection + bias + skip -> out.

typedef __attribute__((ext_vector_type(8))) __bf16 bf16x8;
typedef __attribute__((ext_vector_type(4))) float f32x4;
typedef __attribute__((ext_vector_type(8))) unsigned short u16x8;

constexpr int BB  = 2;
constexpr int LL  = 64;
constexpr int QQ  = 384;
constexpr int TOK = BB * LL * QQ;  // 49152
constexpr float EPSF = 1e-5f;
constexpr float QSCALE = 0.17677669529663687f;  // 32^-0.5

__device__ __forceinline__ unsigned short f2bf(float x) {
  union { __bf16 h; unsigned short u; } c;
  c.h = (__bf16)x;                       // HW cvt (RNE), m240: cast > hand-rolled
  return c.u;
}
__device__ __forceinline__ unsigned pack2(float a, float b) {
  union { __bf16 h[2]; unsigned u; } c;
  c.h[0] = (__bf16)a; c.h[1] = (__bf16)b;  // h[0] = low 16 bits = lower k
  return c.u;
}

// ---------------------------------------------------------------------------
// Kernel 0: W transpose + bf16 cast for all four weight matrices.
// ---------------------------------------------------------------------------
__global__ __launch_bounds__(256) void transpose_w_kernel(
    const float* __restrict__ wq, const float* __restrict__ wk,
    const float* __restrict__ wv, const float* __restrict__ wp,
    unsigned short* __restrict__ tq, unsigned short* __restrict__ tk,
    unsigned short* __restrict__ tv, unsigned short* __restrict__ tp)
{
  const int e = blockIdx.x * 256 + threadIdx.x;  // 0..16383
  const int o = (e & 127) * 128 + (e >> 7);
  tq[o] = f2bf(wq[e]);
  tk[o] = f2bf(wk[e]);
  tv[o] = f2bf(wv[e]);
  tp[o] = f2bf(wp[e]);
}

// ---------------------------------------------------------------------------
// Kernel 1: fused q/k/v LN + MFMA projection (R5 structure, cast-based cvt).
// 2304 blocks; block = 64 tokens of one tensor.
// ---------------------------------------------------------------------------
__global__ __launch_bounds__(256) void ln_proj_all(
    const float* __restrict__ inq, const float* __restrict__ ink,
    const float* __restrict__ inv,
    const float* __restrict__ gq, const float* __restrict__ bq,
    const float* __restrict__ gk, const float* __restrict__ bk,
    const float* __restrict__ gv, const float* __restrict__ bv,
    const unsigned short* __restrict__ wtq, const unsigned short* __restrict__ wtk,
    const unsigned short* __restrict__ wtv,
    const float* __restrict__ biq, const float* __restrict__ bik,
    const float* __restrict__ biv,
    unsigned short* __restrict__ oq, unsigned short* __restrict__ ok,
    unsigned short* __restrict__ ovt)
{
  __shared__ __align__(16) unsigned short Xs[64 * 128];  // 16KB, reused as Tr
  const int bid = blockIdx.x;
  const int seg = (bid >= 1536) ? 2 : (bid >= 768 ? 1 : 0);
  const float* in    = (seg == 0) ? inq : (seg == 1) ? ink : inv;
  const float* gamma = (seg == 0) ? gq  : (seg == 1) ? gk  : gv;
  const float* beta  = (seg == 0) ? bq  : (seg == 1) ? bk  : bv;
  const unsigned short* wt = (seg == 0) ? wtq : (seg == 1) ? wtk : wtv;
  const float* bias  = (seg == 0) ? biq : (seg == 1) ? bik : biv;
  const float scale  = (seg == 0) ? QSCALE : 1.0f;

  const int tid = threadIdx.x, wave = tid >> 6, lane = tid & 63;
  const int tile0 = (bid - seg * 768) * 64;
  const int sl = lane & 15;          // 16 lanes per token
  const float4* g4 = (const float4*)gamma;
  const float4* be4 = (const float4*)beta;
  const float4 g0 = g4[sl * 2], g1 = g4[sl * 2 + 1];
  const float4 b0 = be4[sl * 2], b1 = be4[sl * 2 + 1];

  for (int it = 0; it < 4; ++it) {
    const int tl = wave * 16 + it * 4 + (lane >> 4);
    const int tg = tile0 + tl;
    const int b = tg / 24576; const int rem = tg - b * 24576;
    const int l = rem / 384;  const int t = rem - l * 384;
    const int n = t >> 6, w = t & 63;
    const float4* src = (const float4*)(in + (((size_t)((b * 6 + n) * 64 + l) * 64 + w) << 7));
    const float4 a = src[sl * 2], c = src[sl * 2 + 1];
    float sum = a.x + a.y + a.z + a.w + c.x + c.y + c.z + c.w;
    float sq = a.x * a.x + a.y * a.y + a.z * a.z + a.w * a.w
             + c.x * c.x + c.y * c.y + c.z * c.z + c.w * c.w;
#pragma unroll
    for (int o = 8; o >= 1; o >>= 1) { sum += __shfl_xor(sum, o); sq += __shfl_xor(sq, o); }
    const float mean = sum * (1.f / 128.f);
    const float var = sq * (1.f / 128.f) - mean * mean;
    const float rstd = rsqrtf(var + EPSF);
    unsigned short u[8];
    u[0] = f2bf((a.x - mean) * rstd * g0.x + b0.x);
    u[1] = f2bf((a.y - mean) * rstd * g0.y + b0.y);
    u[2] = f2bf((a.z - mean) * rstd * g0.z + b0.z);
    u[3] = f2bf((a.w - mean) * rstd * g0.w + b0.w);
    u[4] = f2bf((c.x - mean) * rstd * g1.x + b1.x);
    u[5] = f2bf((c.y - mean) * rstd * g1.y + b1.y);
    u[6] = f2bf((c.z - mean) * rstd * g1.z + b1.z);
    u[7] = f2bf((c.w - mean) * rstd * g1.w + b1.w);
    unsigned short* dst = &Xs[(tl * 128 + sl * 8) ^ ((tl & 7) << 3)];
#pragma unroll
    for (int j = 0; j < 8; ++j) dst[j] = u[j];
  }
  __syncthreads();

  const int lr = lane & 15, lg = lane >> 4;
  f32x4 accn[8];
#pragma unroll
  for (int i = 0; i < 8; ++i) accn[i] = (f32x4)0.f;
#pragma unroll
  for (int ks = 0; ks < 4; ++ks) {
    const bf16x8 xa = *(const bf16x8*)&Xs[((wave * 16 + lr) * 128 + ks * 32 + lg * 8) ^ ((lr & 7) << 3)];
#pragma unroll
    for (int nt = 0; nt < 8; ++nt) {
      const bf16x8 wb = *(const bf16x8*)(wt + (size_t)(nt * 16 + lr) * 128 + ks * 32 + lg * 8);
      accn[nt] = __builtin_amdgcn_mfma_f32_16x16x32_bf16(xa, wb, accn[nt], 0, 0, 0);
    }
  }

  __syncthreads();  // all Xs reads done; reuse as transpose buffer
  unsigned short* Tr = Xs;

  if (seg < 2) {
#pragma unroll
    for (int nt = 0; nt < 8; ++nt) {
      const float bvv = bias[nt * 16 + lr];
#pragma unroll
      for (int r = 0; r < 4; ++r) {
        const int rowl = wave * 16 + lg * 4 + r;
        Tr[(rowl * 128 + nt * 16 + lr) ^ ((rowl & 7) << 3)] =
            f2bf((accn[nt][r] + bvv) * scale);
      }
    }
    __syncthreads();
    unsigned short* out = (seg == 0) ? oq : ok;
#pragma unroll
    for (int i = 0; i < 4; ++i) {
      const int lin = i * 256 + tid;           // 0..1023
      const int rowl = lin >> 4, ch = lin & 15;
      const u16x8 val = *(const u16x8*)&Tr[(rowl * 128 + ch * 8) ^ ((rowl & 7) << 3)];
      *(u16x8*)(out + (size_t)(tile0 + rowl) * 128 + ch * 8) = val;
    }
  } else {
    // V: Tr[col 128][row 64] (transposed), then store vpt[bl][hd][t].
#pragma unroll
    for (int nt = 0; nt < 8; ++nt) {
      const float bvv = bias[nt * 16 + lr];
#pragma unroll
      for (int r = 0; r < 4; ++r) {
        const int col = nt * 16 + lr;
        const int rowl = wave * 16 + lg * 4 + r;
        Tr[(col * 64 + rowl) ^ ((col & 7) << 3)] = f2bf(accn[nt][r] + bvv);
      }
    }
    __syncthreads();
    const int bwin = tile0 / 384;    // b*64 + l
    const int t0 = tile0 - bwin * 384;
#pragma unroll
    for (int i = 0; i < 4; ++i) {
      const int lin = i * 256 + tid;           // 0..1023
      const int col = lin >> 3, ch = lin & 7;  // col = h*32+d
      const u16x8 val = *(const u16x8*)&Tr[(col * 64 + ch * 8) ^ ((col & 7) << 3)];
      *(u16x8*)(ovt + ((size_t)bwin * 128 + col) * 384 + t0 + ch * 8) = val;
    }
  }
}

// ---------------------------------------------------------------------------
// Kernel 2: fused attention + mean-over-N + output projection + skip.
// Grid: 1024 blocks = (bl 0..127) x (wg 0..7). 256 threads, wave = head.
// Per block: q-rows g = wl*6+n (wl 0..7 local w, n 0..5 view), 48 rows,
// 3 MFMA tiles per wave. Swapped QK^T: s = mfma(K,Q) so each lane holds a
// k-quad per q-row -> packed uint2 P-stores (swizzled), b128 pa reads.
// Epilogue: O -> LDS, mean over n -> Ab(bf16), MFMA @ wpt + bp + skip -> out.
// ---------------------------------------------------------------------------
__global__ __launch_bounds__(256) void attn_fused(
    const unsigned short* __restrict__ qp, const unsigned short* __restrict__ kp,
    const unsigned short* __restrict__ vpt, const unsigned short* __restrict__ wpt,
    const float* __restrict__ bp, const float* __restrict__ skip,
    float* __restrict__ out)
{
  __shared__ __align__(16) float Of[48][132];            // 25.3KB, +4 pad
  __shared__ __align__(16) unsigned short Pl[4][512];    // per-wave [q16][k32]
  __shared__ __align__(16) unsigned short Ab[16][136];   // bf16 A for proj

  const int tid = threadIdx.x, wave = tid >> 6, lane = tid & 63;
  const int lr = lane & 15, lg = lane >> 4;
  const int h = wave;
  const int bid = blockIdx.x;
  const int wg = bid & 7, bl = bid >> 3;
  const int w0 = wg * 8;
  const size_t base = (size_t)bl * (QQ * 128) + h * 32;
  const size_t vtb  = ((size_t)bl * 128 + h * 32) * 384;

  // ---- Q fragments for 3 tiles (rows g = tile*16 + lr; t = n*64 + w0 + wl) ----
  bf16x8 qf[3];
#pragma unroll
  for (int t = 0; t < 3; ++t) {
    const int g = t * 16 + lr;
    const int wl = g / 6, n = g - wl * 6;
    const int tok = n * 64 + w0 + wl;
    qf[t] = *(const bf16x8*)(qp + base + (size_t)tok * 128 + lg * 8);
  }

  f32x4 acc[3][2]; f32x4 sea[3];
#pragma unroll
  for (int t = 0; t < 3; ++t) {
    acc[t][0] = (f32x4)0.f; acc[t][1] = (f32x4)0.f; sea[t] = (f32x4)0.f;
  }
  bf16x8 ones;
#pragma unroll
  for (int i = 0; i < 8; ++i) ones[i] = (__bf16)1.0f;
  const f32x4 zf = (f32x4)0.f;

  unsigned char* pw = (unsigned char*)Pl[wave];
  const int swz = (lr & 3) << 4;           // 16B-granular row swizzle
  const int wrow = lr * 64;

  for (int c = 0; c < 12; ++c) {
    const bf16x8 kf0 = *(const bf16x8*)(kp + base + (size_t)(c * 32 + lr) * 128 + lg * 8);
    const bf16x8 kf1 = *(const bf16x8*)(kp + base + (size_t)(c * 32 + 16 + lr) * 128 + lg * 8);
    const bf16x8 vf0 = *(const bf16x8*)(vpt + vtb + (size_t)lr * 384 + c * 32 + lg * 8);
    const bf16x8 vf1 = *(const bf16x8*)(vpt + vtb + (size_t)(16 + lr) * 384 + c * 32 + lg * 8);

#pragma unroll
    for (int t = 0; t < 3; ++t) {
      // swapped operands: lane holds S[k = 16m + lg*4 + r][q = lr]
      f32x4 s0 = __builtin_amdgcn_mfma_f32_16x16x32_bf16(kf0, qf[t], zf, 0, 0, 0);
      f32x4 s1 = __builtin_amdgcn_mfma_f32_16x16x32_bf16(kf1, qf[t], zf, 0, 0, 0);
      // P = exp(S) (no max-subtract: LN-bounded scores), packed k-quads
      uint2 p0, p1;
      p0.x = pack2(__expf(s0[0]), __expf(s0[1]));
      p0.y = pack2(__expf(s0[2]), __expf(s0[3]));
      p1.x = pack2(__expf(s1[0]), __expf(s1[1]));
      p1.y = pack2(__expf(s1[2]), __expf(s1[3]));
      *(uint2*)(pw + (wrow + (( 0 + lg * 8) ^ swz))) = p0;   // k 0..15 quad
      *(uint2*)(pw + (wrow + ((32 + lg * 8) ^ swz))) = p1;   // k 16..31 quad
      __builtin_amdgcn_sched_barrier(0);
      const bf16x8 pa = *(const bf16x8*)(pw + (wrow + ((lg * 16) ^ swz)));
      acc[t][0] = __builtin_amdgcn_mfma_f32_16x16x32_bf16(pa, vf0, acc[t][0], 0, 0, 0);
      acc[t][1] = __builtin_amdgcn_mfma_f32_16x16x32_bf16(pa, vf1, acc[t][1], 0, 0, 0);
      sea[t]    = __builtin_amdgcn_mfma_f32_16x16x32_bf16(pa, ones, sea[t], 0, 0, 0);
      __builtin_amdgcn_sched_barrier(0);
    }
  }

  // ---- O -> LDS (rows g, cols h*32 + d) ----
#pragma unroll
  for (int t = 0; t < 3; ++t) {
#pragma unroll
    for (int r = 0; r < 4; ++r) {
      const float inv = 1.f / sea[t][r];
      const int g = t * 16 + lg * 4 + r;
      Of[g][h * 32 + lr]      = acc[t][0][r] * inv;
      Of[g][h * 32 + 16 + lr] = acc[t][1][r] * inv;
    }
  }
  __syncthreads();

  // ---- mean over n (6 views) -> Ab bf16 [16][136]; rows 8..15 zeroed ----
#pragma unroll
  for (int i = 0; i < 4; ++i) {
    const int idx = i * 256 + tid;       // 0..1023
    const int wl = idx >> 7, col = idx & 127;
    float s = 0.f;
#pragma unroll
    for (int n = 0; n < 6; ++n) s += Of[wl * 6 + n][col];
    Ab[wl][col] = f2bf(s * (1.f / 6.f));
    Ab[wl + 8][col] = 0;
  }
  __syncthreads();

  // ---- projection: Abar(8x128) @ wp(128x128) via MFMA; wave = 32-col block ----
  f32x4 accp[2];
  accp[0] = (f32x4)0.f; accp[1] = (f32x4)0.f;
#pragma unroll
  for (int ks = 0; ks < 4; ++ks) {
    const bf16x8 af = *(const bf16x8*)&Ab[lr][ks * 32 + lg * 8];
    const bf16x8 wb0 = *(const bf16x8*)(wpt + (size_t)(wave * 32 + lr) * 128 + ks * 32 + lg * 8);
    const bf16x8 wb1 = *(const bf16x8*)(wpt + (size_t)(wave * 32 + 16 + lr) * 128 + ks * 32 + lg * 8);
    accp[0] = __builtin_amdgcn_mfma_f32_16x16x32_bf16(af, wb0, accp[0], 0, 0, 0);
    accp[1] = __builtin_amdgcn_mfma_f32_16x16x32_bf16(af, wb1, accp[1], 0, 0, 0);
  }

  if (lg < 2) {  // valid output rows wl = lg*4 + r < 8
#pragma unroll
    for (int nt = 0; nt < 2; ++nt) {
      const int col = wave * 32 + nt * 16 + lr;
      const float bb = bp[col];
#pragma unroll
      for (int r = 0; r < 4; ++r) {
        const int wl = lg * 4 + r;
        const size_t o = ((size_t)bl * 64 + w0 + wl) * 128 + col;
        out[o] = accp[nt][r] + bb + skip[o];
      }
    }
  }
}

// ---------------------------------------------------------------------------
extern "C" void kernel_launch(void* const* d_in, const int* in_sizes, int n_in,
                              void* d_out, int out_size, void* d_ws, size_t ws_size,
                              hipStream_t stream)
{
  const float* q     = (const float*)d_in[0];
  const float* k     = (const float*)d_in[1];
  const float* v     = (const float*)d_in[2];
  const float* skip  = (const float*)d_in[3];
  const float* lnq_g = (const float*)d_in[4];
  const float* lnq_b = (const float*)d_in[5];
  const float* lnk_g = (const float*)d_in[6];
  const float* lnk_b = (const float*)d_in[7];
  const float* lnv_g = (const float*)d_in[8];
  const float* lnv_b = (const float*)d_in[9];
  const float* wq = (const float*)d_in[10];
  const float* bq = (const float*)d_in[11];
  const float* wk = (const float*)d_in[12];
  const float* bk = (const float*)d_in[13];
  const float* wv = (const float*)d_in[14];
  const float* bv = (const float*)d_in[15];
  const float* wp = (const float*)d_in[16];
  const float* bp = (const float*)d_in[17];
  float* out = (float*)d_out;

  const size_t PROJ = (size_t)TOK * 128;  // elements
  unsigned short* qp  = (unsigned short*)d_ws;
  unsigned short* kp  = qp + PROJ;
  unsigned short* vpt = kp + PROJ;        // [bl][hd][t] transposed V
  unsigned short* wtq = vpt + PROJ;
  unsigned short* wtk = wtq + 16384;
  unsigned short* wtv = wtk + 16384;
  unsigned short* wtp = wtv + 16384;

  transpose_w_kernel<<<64, 256, 0, stream>>>(wq, wk, wv, wp, wtq, wtk, wtv, wtp);
  ln_proj_all<<<2304, 256, 0, stream>>>(q, k, v, lnq_g, lnq_b, lnk_g, lnk_b,
                                        lnv_g, lnv_b, wtq, wtk, wtv,
                                        bq, bk, bv, qp, kp, vpt);
  attn_fused<<<1024, 256, 0, stream>>>(qp, kp, vpt, wtp, bp, skip, out);
}

// Round 8
// 189.873 us; speedup vs baseline: 1.2640x; 1.0927x over previous
//
#include <hip/hip_runtime.h>
#include <hip/hip_bf16.h>

// CrossWinAttention — bf16 MFMA pipeline, round 7 (resubmit; round 7 never ran).
// B=2, N=6, X=Y=W1=W2=8, D=128, HEADS=4, DIM_HEAD=32; L=64, Q=384, TOK=49152.
//
//   0) transpose_w_kernel : wq/wk/wv/wp (f32 [k][j]) -> bf16 [j][k]
//   1) ln_proj_all        : LN + MFMA proj; W staged in LDS (swizzled) so the
//                           32 B-frag fetches are ds_read_b128 not serial L2;
//                           V written TRANSPOSED (vpt[bl][hd][t])
//   2) attn_fused         : block=(bl, 8-w group), wave=head; swapped QK^T,
//                           packed P-stores, PV + ones-MFMA row sums; in-block
//                           mean over n + MFMA out-proj + bias + skip -> out.

typedef __attribute__((ext_vector_type(8))) __bf16 bf16x8;
typedef __attribute__((ext_vector_type(4))) float f32x4;
typedef __attribute__((ext_vector_type(8))) unsigned short u16x8;

constexpr int BB  = 2;
constexpr int LL  = 64;
constexpr int QQ  = 384;
constexpr int TOK = BB * LL * QQ;  // 49152
constexpr float EPSF = 1e-5f;
constexpr float QSCALE = 0.17677669529663687f;  // 32^-0.5

__device__ __forceinline__ unsigned short f2bf(float x) {
  union { __bf16 h; unsigned short u; } c;
  c.h = (__bf16)x;                       // HW cvt (RNE)
  return c.u;
}
__device__ __forceinline__ unsigned pack2(float a, float b) {
  union { __bf16 h[2]; unsigned u; } c;
  c.h[0] = (__bf16)a; c.h[1] = (__bf16)b;  // h[0] = low 16 bits = lower k
  return c.u;
}

// ---------------------------------------------------------------------------
// Kernel 0: W transpose + bf16 cast for all four weight matrices.
// ---------------------------------------------------------------------------
__global__ __launch_bounds__(256) void transpose_w_kernel(
    const float* __restrict__ wq, const float* __restrict__ wk,
    const float* __restrict__ wv, const float* __restrict__ wp,
    unsigned short* __restrict__ tq, unsigned short* __restrict__ tk,
    unsigned short* __restrict__ tv, unsigned short* __restrict__ tp)
{
  const int e = blockIdx.x * 256 + threadIdx.x;  // 0..16383
  const int o = (e & 127) * 128 + (e >> 7);
  tq[o] = f2bf(wq[e]);
  tk[o] = f2bf(wk[e]);
  tv[o] = f2bf(wv[e]);
  tp[o] = f2bf(wp[e]);
}

// ---------------------------------------------------------------------------
// Kernel 1: fused q/k/v LN + MFMA projection. 2304 blocks; block = 64 tokens.
// W staged per-block into LDS (XOR-swizzled) -> B-frags via ds_read_b128.
// ---------------------------------------------------------------------------
__global__ __launch_bounds__(256) void ln_proj_all(
    const float* __restrict__ inq, const float* __restrict__ ink,
    const float* __restrict__ inv,
    const float* __restrict__ gq, const float* __restrict__ bq,
    const float* __restrict__ gk, const float* __restrict__ bk,
    const float* __restrict__ gv, const float* __restrict__ bv,
    const unsigned short* __restrict__ wtq, const unsigned short* __restrict__ wtk,
    const unsigned short* __restrict__ wtv,
    const float* __restrict__ biq, const float* __restrict__ bik,
    const float* __restrict__ biv,
    unsigned short* __restrict__ oq, unsigned short* __restrict__ ok,
    unsigned short* __restrict__ ovt)
{
  __shared__ __align__(16) unsigned short Xs[64 * 128];   // 16 KB, reused as Tr
  __shared__ __align__(16) unsigned short Ws[128 * 128];  // 32 KB swizzled W
  const int bid = blockIdx.x;
  const int seg = (bid >= 1536) ? 2 : (bid >= 768 ? 1 : 0);
  const float* in    = (seg == 0) ? inq : (seg == 1) ? ink : inv;
  const float* gamma = (seg == 0) ? gq  : (seg == 1) ? gk  : gv;
  const float* beta  = (seg == 0) ? bq  : (seg == 1) ? bk  : bv;
  const unsigned short* wt = (seg == 0) ? wtq : (seg == 1) ? wtk : wtv;
  const float* bias  = (seg == 0) ? biq : (seg == 1) ? bik : biv;
  const float scale  = (seg == 0) ? QSCALE : 1.0f;

  const int tid = threadIdx.x, wave = tid >> 6, lane = tid & 63;
  const int tile0 = (bid - seg * 768) * 64;

  // ---- W -> LDS, rows XOR-swizzled (read pattern = col-slice per lane) ----
#pragma unroll
  for (int i = 0; i < 8; ++i) {
    const int cw = i * 256 + tid;          // 8-u16 chunk id, 0..2047
    const int row = cw >> 4, c8 = cw & 15;
    const u16x8 wv = *(const u16x8*)(wt + (size_t)cw * 8);
    *(u16x8*)&Ws[(row * 128 + c8 * 8) ^ ((row & 7) << 3)] = wv;
  }

  // ---- LN -> Xs (4 tokens in parallel per wave, 16 lanes each) ----
  const int sl = lane & 15;
  const float4* g4 = (const float4*)gamma;
  const float4* be4 = (const float4*)beta;
  const float4 g0 = g4[sl * 2], g1 = g4[sl * 2 + 1];
  const float4 b0 = be4[sl * 2], b1 = be4[sl * 2 + 1];

  for (int it = 0; it < 4; ++it) {
    const int tl = wave * 16 + it * 4 + (lane >> 4);
    const int tg = tile0 + tl;
    const int b = tg / 24576; const int rem = tg - b * 24576;
    const int l = rem / 384;  const int t = rem - l * 384;
    const int n = t >> 6, w = t & 63;
    const float4* src = (const float4*)(in + (((size_t)((b * 6 + n) * 64 + l) * 64 + w) << 7));
    const float4 a = src[sl * 2], c = src[sl * 2 + 1];
    float sum = a.x + a.y + a.z + a.w + c.x + c.y + c.z + c.w;
    float sq = a.x * a.x + a.y * a.y + a.z * a.z + a.w * a.w
             + c.x * c.x + c.y * c.y + c.z * c.z + c.w * c.w;
#pragma unroll
    for (int o = 8; o >= 1; o >>= 1) { sum += __shfl_xor(sum, o); sq += __shfl_xor(sq, o); }
    const float mean = sum * (1.f / 128.f);
    const float var = sq * (1.f / 128.f) - mean * mean;
    const float rstd = rsqrtf(var + EPSF);
    unsigned short u[8];
    u[0] = f2bf((a.x - mean) * rstd * g0.x + b0.x);
    u[1] = f2bf((a.y - mean) * rstd * g0.y + b0.y);
    u[2] = f2bf((a.z - mean) * rstd * g0.z + b0.z);
    u[3] = f2bf((a.w - mean) * rstd * g0.w + b0.w);
    u[4] = f2bf((c.x - mean) * rstd * g1.x + b1.x);
    u[5] = f2bf((c.y - mean) * rstd * g1.y + b1.y);
    u[6] = f2bf((c.z - mean) * rstd * g1.z + b1.z);
    u[7] = f2bf((c.w - mean) * rstd * g1.w + b1.w);
    unsigned short* dst = &Xs[(tl * 128 + sl * 8) ^ ((tl & 7) << 3)];
#pragma unroll
    for (int j = 0; j < 8; ++j) dst[j] = u[j];
  }
  __syncthreads();

  // ---- MFMA: A from Xs, B from Ws (both ds_read_b128, conflict-free) ----
  const int lr = lane & 15, lg = lane >> 4;
  f32x4 accn[8];
#pragma unroll
  for (int i = 0; i < 8; ++i) accn[i] = (f32x4)0.f;
#pragma unroll
  for (int ks = 0; ks < 4; ++ks) {
    const bf16x8 xa = *(const bf16x8*)&Xs[((wave * 16 + lr) * 128 + ks * 32 + lg * 8) ^ ((lr & 7) << 3)];
#pragma unroll
    for (int nt = 0; nt < 8; ++nt) {
      const bf16x8 wb = *(const bf16x8*)&Ws[((nt * 16 + lr) * 128 + ks * 32 + lg * 8) ^ ((lr & 7) << 3)];
      accn[nt] = __builtin_amdgcn_mfma_f32_16x16x32_bf16(xa, wb, accn[nt], 0, 0, 0);
    }
  }

  __syncthreads();  // all Xs reads done; reuse as transpose buffer
  unsigned short* Tr = Xs;

  if (seg < 2) {
#pragma unroll
    for (int nt = 0; nt < 8; ++nt) {
      const float bvv = bias[nt * 16 + lr];
#pragma unroll
      for (int r = 0; r < 4; ++r) {
        const int rowl = wave * 16 + lg * 4 + r;
        Tr[(rowl * 128 + nt * 16 + lr) ^ ((rowl & 7) << 3)] =
            f2bf((accn[nt][r] + bvv) * scale);
      }
    }
    __syncthreads();
    unsigned short* out = (seg == 0) ? oq : ok;
#pragma unroll
    for (int i = 0; i < 4; ++i) {
      const int lin = i * 256 + tid;           // 0..1023
      const int rowl = lin >> 4, ch = lin & 15;
      const u16x8 val = *(const u16x8*)&Tr[(rowl * 128 + ch * 8) ^ ((rowl & 7) << 3)];
      *(u16x8*)(out + (size_t)(tile0 + rowl) * 128 + ch * 8) = val;
    }
  } else {
    // V: Tr[col 128][row 64] (transposed), then store vpt[bl][hd][t].
#pragma unroll
    for (int nt = 0; nt < 8; ++nt) {
      const float bvv = bias[nt * 16 + lr];
#pragma unroll
      for (int r = 0; r < 4; ++r) {
        const int col = nt * 16 + lr;
        const int rowl = wave * 16 + lg * 4 + r;
        Tr[(col * 64 + rowl) ^ ((col & 7) << 3)] = f2bf(accn[nt][r] + bvv);
      }
    }
    __syncthreads();
    const int bwin = tile0 / 384;    // b*64 + l
    const int t0 = tile0 - bwin * 384;
#pragma unroll
    for (int i = 0; i < 4; ++i) {
      const int lin = i * 256 + tid;           // 0..1023
      const int col = lin >> 3, ch = lin & 7;  // col = h*32+d
      const u16x8 val = *(const u16x8*)&Tr[(col * 64 + ch * 8) ^ ((col & 7) << 3)];
      *(u16x8*)(ovt + ((size_t)bwin * 128 + col) * 384 + t0 + ch * 8) = val;
    }
  }
}

// ---------------------------------------------------------------------------
// Kernel 2: fused attention + mean-over-N + output projection + skip.
// Grid: 1024 blocks = (bl 0..127) x (wg 0..7). 256 threads, wave = head.
// ---------------------------------------------------------------------------
__global__ __launch_bounds__(256, 3) void attn_fused(
    const unsigned short* __restrict__ qp, const unsigned short* __restrict__ kp,
    const unsigned short* __restrict__ vpt, const unsigned short* __restrict__ wpt,
    const float* __restrict__ bp, const float* __restrict__ skip,
    float* __restrict__ out)
{
  __shared__ __align__(16) float Of[48][132];            // 25.3KB, +4 pad
  __shared__ __align__(16) unsigned short Pl[4][512];    // per-wave [q16][k32]
  __shared__ __align__(16) unsigned short Ab[16][136];   // bf16 A for proj

  const int tid = threadIdx.x, wave = tid >> 6, lane = tid & 63;
  const int lr = lane & 15, lg = lane >> 4;
  const int h = wave;
  const int bid = blockIdx.x;
  const int wg = bid & 7, bl = bid >> 3;
  const int w0 = wg * 8;
  const size_t base = (size_t)bl * (QQ * 128) + h * 32;
  const size_t vtb  = ((size_t)bl * 128 + h * 32) * 384;

  // ---- Q fragments for 3 tiles (rows g = tile*16 + lr; t = n*64 + w0 + wl) ----
  bf16x8 qf[3];
#pragma unroll
  for (int t = 0; t < 3; ++t) {
    const int g = t * 16 + lr;
    const int wl = g / 6, n = g - wl * 6;
    const int tok = n * 64 + w0 + wl;
    qf[t] = *(const bf16x8*)(qp + base + (size_t)tok * 128 + lg * 8);
  }

  f32x4 acc[3][2]; f32x4 sea[3];
#pragma unroll
  for (int t = 0; t < 3; ++t) {
    acc[t][0] = (f32x4)0.f; acc[t][1] = (f32x4)0.f; sea[t] = (f32x4)0.f;
  }
  bf16x8 ones;
#pragma unroll
  for (int i = 0; i < 8; ++i) ones[i] = (__bf16)1.0f;
  const f32x4 zf = (f32x4)0.f;

  unsigned char* pw = (unsigned char*)Pl[wave];
  const int swz = (lr & 3) << 4;           // 16B-granular row swizzle
  const int wrow = lr * 64;

  for (int c = 0; c < 12; ++c) {
    const bf16x8 kf0 = *(const bf16x8*)(kp + base + (size_t)(c * 32 + lr) * 128 + lg * 8);
    const bf16x8 kf1 = *(const bf16x8*)(kp + base + (size_t)(c * 32 + 16 + lr) * 128 + lg * 8);
    const bf16x8 vf0 = *(const bf16x8*)(vpt + vtb + (size_t)lr * 384 + c * 32 + lg * 8);
    const bf16x8 vf1 = *(const bf16x8*)(vpt + vtb + (size_t)(16 + lr) * 384 + c * 32 + lg * 8);

#pragma unroll
    for (int t = 0; t < 3; ++t) {
      // swapped operands: lane holds S[k = 16m + lg*4 + r][q = lr]
      f32x4 s0 = __builtin_amdgcn_mfma_f32_16x16x32_bf16(kf0, qf[t], zf, 0, 0, 0);
      f32x4 s1 = __builtin_amdgcn_mfma_f32_16x16x32_bf16(kf1, qf[t], zf, 0, 0, 0);
      // P = exp(S) (no max-subtract: LN-bounded scores), packed k-quads
      uint2 p0, p1;
      p0.x = pack2(__expf(s0[0]), __expf(s0[1]));
      p0.y = pack2(__expf(s0[2]), __expf(s0[3]));
      p1.x = pack2(__expf(s1[0]), __expf(s1[1]));
      p1.y = pack2(__expf(s1[2]), __expf(s1[3]));
      *(uint2*)(pw + (wrow + (( 0 + lg * 8) ^ swz))) = p0;   // k 0..15 quad
      *(uint2*)(pw + (wrow + ((32 + lg * 8) ^ swz))) = p1;   // k 16..31 quad
      // pointer-based LDS RAW: compiler inserts the lgkmcnt wait itself
      const bf16x8 pa = *(const bf16x8*)(pw + (wrow + ((lg * 16) ^ swz)));
      acc[t][0] = __builtin_amdgcn_mfma_f32_16x16x32_bf16(pa, vf0, acc[t][0], 0, 0, 0);
      acc[t][1] = __builtin_amdgcn_mfma_f32_16x16x32_bf16(pa, vf1, acc[t][1], 0, 0, 0);
      sea[t]    = __builtin_amdgcn_mfma_f32_16x16x32_bf16(pa, ones, sea[t], 0, 0, 0);
    }
  }

  // ---- O -> LDS (rows g, cols h*32 + d) ----
#pragma unroll
  for (int t = 0; t < 3; ++t) {
#pragma unroll
    for (int r = 0; r < 4; ++r) {
      const float inv = 1.f / sea[t][r];
      const int g = t * 16 + lg * 4 + r;
      Of[g][h * 32 + lr]      = acc[t][0][r] * inv;
      Of[g][h * 32 + 16 + lr] = acc[t][1][r] * inv;
    }
  }
  __syncthreads();

  // ---- mean over n (6 views) -> Ab bf16 [16][136]; rows 8..15 zeroed ----
#pragma unroll
  for (int i = 0; i < 4; ++i) {
    const int idx = i * 256 + tid;       // 0..1023
    const int wl = idx >> 7, col = idx & 127;
    float s = 0.f;
#pragma unroll
    for (int n = 0; n < 6; ++n) s += Of[wl * 6 + n][col];
    Ab[wl][col] = f2bf(s * (1.f / 6.f));
    Ab[wl + 8][col] = 0;
  }
  __syncthreads();

  // ---- projection: Abar(8x128) @ wp(128x128) via MFMA; wave = 32-col block ----
  f32x4 accp[2];
  accp[0] = (f32x4)0.f; accp[1] = (f32x4)0.f;
#pragma unroll
  for (int ks = 0; ks < 4; ++ks) {
    const bf16x8 af = *(const bf16x8*)&Ab[lr][ks * 32 + lg * 8];
    const bf16x8 wb0 = *(const bf16x8*)(wpt + (size_t)(wave * 32 + lr) * 128 + ks * 32 + lg * 8);
    const bf16x8 wb1 = *(const bf16x8*)(wpt + (size_t)(wave * 32 + 16 + lr) * 128 + ks * 32 + lg * 8);
    accp[0] = __builtin_amdgcn_mfma_f32_16x16x32_bf16(af, wb0, accp[0], 0, 0, 0);
    accp[1] = __builtin_amdgcn_mfma_f32_16x16x32_bf16(af, wb1, accp[1], 0, 0, 0);
  }

  if (lg < 2) {  // valid output rows wl = lg*4 + r < 8
#pragma unroll
    for (int nt = 0; nt < 2; ++nt) {
      const int col = wave * 32 + nt * 16 + lr;
      const float bb = bp[col];
#pragma unroll
      for (int r = 0; r < 4; ++r) {
        const int wl = lg * 4 + r;
        const size_t o = ((size_t)bl * 64 + w0 + wl) * 128 + col;
        out[o] = accp[nt][r] + bb + skip[o];
      }
    }
  }
}

// ---------------------------------------------------------------------------
extern "C" void kernel_launch(void* const* d_in, const int* in_sizes, int n_in,
                              void* d_out, int out_size, void* d_ws, size_t ws_size,
                              hipStream_t stream)
{
  const float* q     = (const float*)d_in[0];
  const float* k     = (const float*)d_in[1];
  const float* v     = (const float*)d_in[2];
  const float* skip  = (const float*)d_in[3];
  const float* lnq_g = (const float*)d_in[4];
  const float* lnq_b = (const float*)d_in[5];
  const float* lnk_g = (const float*)d_in[6];
  const float* lnk_b = (const float*)d_in[7];
  const float* lnv_g = (const float*)d_in[8];
  const float* lnv_b = (const float*)d_in[9];
  const float* wq = (const float*)d_in[10];
  const float* bq = (const float*)d_in[11];
  const float* wk = (const float*)d_in[12];
  const float* bk = (const float*)d_in[13];
  const float* wv = (const float*)d_in[14];
  const float* bv = (const float*)d_in[15];
  const float* wp = (const float*)d_in[16];
  const float* bp = (const float*)d_in[17];
  float* out = (float*)d_out;

  const size_t PROJ = (size_t)TOK * 128;  // elements
  unsigned short* qp  = (unsigned short*)d_ws;
  unsigned short* kp  = qp + PROJ;
  unsigned short* vpt = kp + PROJ;        // [bl][hd][t] transposed V
  unsigned short* wtq = vpt + PROJ;
  unsigned short* wtk = wtq + 16384;
  unsigned short* wtv = wtk + 16384;
  unsigned short* wtp = wtv + 16384;

  transpose_w_kernel<<<64, 256, 0, stream>>>(wq, wk, wv, wp, wtq, wtk, wtv, wtp);
  ln_proj_all<<<2304, 256, 0, stream>>>(q, k, v, lnq_g, lnq_b, lnk_g, lnk_b,
                                        lnv_g, lnv_b, wtq, wtk, wtv,
                                        bq, bk, bv, qp, kp, vpt);
  attn_fused<<<1024, 256, 0, stream>>>(qp, kp, vpt, wtp, bp, skip, out);
}